// Round 3
// baseline (695.107 us; speedup 1.0000x reference)
//
#include <hip/hip_runtime.h>
#include <math.h>

#define BSZ 16
#define DIMM 4096
#define NKVH 8
#define HD 128
#define SEQ 4096
#define NSPLIT 16
#define SPLITLEN 256
#define RPAD 65

// ---------------------------------------------------------------------------
// Streaming skinny GEMV, per-wave, 2 consecutive rows, no block barriers.
// x (256 KB) is L2/L3-resident: read it straight from global per lane instead
// of LDS-staging (stage+__syncthreads cost a vmcnt(0) barrier drain per chunk
// — the m97-style stall). W rows streamed float4, each byte read once.
// res[r] valid in all lanes for batch b = lane>>2 after wave-local reduce.
// ---------------------------------------------------------------------------
__device__ __forceinline__ void gemv2_stream(
    const float* __restrict__ xg, const float* __restrict__ W, int rbase,
    float* __restrict__ rbuf /* per-wave 16*RPAD floats */, float res[2],
    int lane) {
  float acc0[16], acc1[16];
#pragma unroll
  for (int b = 0; b < 16; ++b) { acc0[b] = 0.f; acc1[b] = 0.f; }
  const float* wp = W + (size_t)rbase * DIMM + (lane << 2);
#pragma unroll 2
  for (int c = 0; c < 16; ++c) {
    float4 w0 = *(const float4*)(wp + c * 256);
    float4 w1 = *(const float4*)(wp + DIMM + c * 256);
    const float* xp = xg + c * 256 + (lane << 2);
#pragma unroll
    for (int b = 0; b < 16; ++b) {
      float4 xv = *(const float4*)(xp + (size_t)b * DIMM);
      acc0[b] = fmaf(w0.x, xv.x, acc0[b]);
      acc0[b] = fmaf(w0.y, xv.y, acc0[b]);
      acc0[b] = fmaf(w0.z, xv.z, acc0[b]);
      acc0[b] = fmaf(w0.w, xv.w, acc0[b]);
      acc1[b] = fmaf(w1.x, xv.x, acc1[b]);
      acc1[b] = fmaf(w1.y, xv.y, acc1[b]);
      acc1[b] = fmaf(w1.z, xv.z, acc1[b]);
      acc1[b] = fmaf(w1.w, xv.w, acc1[b]);
    }
  }
  // Wave-local cross-lane reduction through a per-wave LDS slice. No
  // __syncthreads needed: buffer is wave-private; intra-wave DS ordering is
  // program order (wave_barrier = free scheduling fence for safety).
  const int bb = lane >> 2, j = lane & 3;
#pragma unroll
  for (int r = 0; r < 2; ++r) {
    const float* a = r ? acc1 : acc0;
    __builtin_amdgcn_wave_barrier();
#pragma unroll
    for (int b = 0; b < 16; ++b) rbuf[b * RPAD + lane] = a[b];
    __builtin_amdgcn_wave_barrier();
    float s = 0.f;
#pragma unroll
    for (int k = 0; k < 16; ++k) s += rbuf[bb * RPAD + j * 16 + k];
    s += __shfl_xor(s, 1);
    s += __shfl_xor(s, 2);
    res[r] = s;
  }
}

// ---------------------------------------------------------------------------
// Kernel 1: QKV projection + RoPE + in-place KV-cache update at pos 4095.
// rows 0..4095 = wq, 4096..5119 = wk, 5120..6143 = wv. 8 rows/block, 768 blk.
// ---------------------------------------------------------------------------
__global__ __launch_bounds__(256) void qkv_kernel(
    const float* __restrict__ x, const float* __restrict__ wq,
    const float* __restrict__ wk, const float* __restrict__ wv,
    const float* __restrict__ fcos, const float* __restrict__ fsin,
    float* __restrict__ q_ws, float* __restrict__ ckw, float* __restrict__ cvw) {
  __shared__ float red[4][16 * RPAD];
  const int tid = threadIdx.x;
  const int lane = tid & 63;
  const int wave = tid >> 6;
  const int row0 = blockIdx.x * 8 + wave * 2;

  const float* W;
  int rbase, kind;  // 0=q, 1=k, 2=v
  if (row0 < 4096)      { W = wq; rbase = row0;        kind = 0; }
  else if (row0 < 5120) { W = wk; rbase = row0 - 4096; kind = 1; }
  else                  { W = wv; rbase = row0 - 5120; kind = 2; }

  float res[2];
  gemv2_stream(x, W, rbase, red[wave], res, lane);

  if (kind <= 1) {  // RoPE: rows (rbase, rbase+1) form one even/odd pair
    int i = (rbase & 127) >> 1;
    float c = fcos[i], s = fsin[i];
    float a = res[0], b2 = res[1];
    res[0] = a * c - b2 * s;
    res[1] = a * s + b2 * c;
  }
  if ((lane & 3) == 0) {
    int b = lane >> 2;
    if (kind == 0) {
      q_ws[(size_t)b * 4096 + rbase]     = res[0];
      q_ws[(size_t)b * 4096 + rbase + 1] = res[1];
    } else {
      int kvh = rbase >> 7, dpos = rbase & 127;
      float* dst = (kind == 1) ? ckw : cvw;
      size_t off = ((size_t)(b * 4096 + 4095) * 8 + kvh) * 128 + dpos;
      dst[off]     = res[0];
      dst[off + 1] = res[1];
    }
  }
}

// ---------------------------------------------------------------------------
// Kernel 2: flash-decode attention partials. Branchless (pos 4095 already in
// cache). grid (NSPLIT, NKVH, BSZ); block 256; 4 GQA heads, 256 keys/block.
// ---------------------------------------------------------------------------
__global__ __launch_bounds__(256) void attn_kernel(
    const float* __restrict__ ck, const float* __restrict__ cv,
    const float* __restrict__ q_ws, float* __restrict__ ml_ws,
    float* __restrict__ opart) {
  __shared__ float sc[SPLITLEN * 4];   // [p][h]
  __shared__ float part[32 * 128];     // [half*16 + wave*4 + h][d]
  const int tid = threadIdx.x, lane = tid & 63, wave = tid >> 6;
  const int split = blockIdx.x, kvh = blockIdx.y, b = blockIdx.z;
  const int p0 = split * SPLITLEN;
  const float scale = 0.08838834764831845f;  // 1/sqrt(128)

  // ---- Phase 1: scores = q . k (8 lanes per row, shuffle reduce) ----
  {
    const int dsub = (lane & 7) << 2;
    const int prow = lane >> 3;
    float4 q4[4][4];
#pragma unroll
    for (int h = 0; h < 4; ++h)
#pragma unroll
      for (int j = 0; j < 4; ++j) {
        float4 t = *(const float4*)(q_ws + (size_t)b * 4096 + (kvh * 4 + h) * 128 + j * 32 + dsub);
        q4[h][j] = make_float4(t.x * scale, t.y * scale, t.z * scale, t.w * scale);
      }
    const float* kbase =
        ck + ((size_t)(b * 4096 + p0 + wave * 64 + prow) * 8 + kvh) * 128 + dsub;
#pragma unroll 2
    for (int it = 0; it < 8; ++it) {
      const float* kp = kbase + it * 8 * 1024;  // 8 rows x 1024 floats apart
      float s0 = 0, s1 = 0, s2 = 0, s3 = 0;
#pragma unroll
      for (int j = 0; j < 4; ++j) {
        float4 k4 = *(const float4*)(kp + j * 32);
        s0 = fmaf(k4.x, q4[0][j].x, s0); s0 = fmaf(k4.y, q4[0][j].y, s0);
        s0 = fmaf(k4.z, q4[0][j].z, s0); s0 = fmaf(k4.w, q4[0][j].w, s0);
        s1 = fmaf(k4.x, q4[1][j].x, s1); s1 = fmaf(k4.y, q4[1][j].y, s1);
        s1 = fmaf(k4.z, q4[1][j].z, s1); s1 = fmaf(k4.w, q4[1][j].w, s1);
        s2 = fmaf(k4.x, q4[2][j].x, s2); s2 = fmaf(k4.y, q4[2][j].y, s2);
        s2 = fmaf(k4.z, q4[2][j].z, s2); s2 = fmaf(k4.w, q4[2][j].w, s2);
        s3 = fmaf(k4.x, q4[3][j].x, s3); s3 = fmaf(k4.y, q4[3][j].y, s3);
        s3 = fmaf(k4.z, q4[3][j].z, s3); s3 = fmaf(k4.w, q4[3][j].w, s3);
      }
#pragma unroll
      for (int m = 1; m <= 4; m <<= 1) {
        s0 += __shfl_xor(s0, m); s1 += __shfl_xor(s1, m);
        s2 += __shfl_xor(s2, m); s3 += __shfl_xor(s3, m);
      }
      if ((lane & 7) == 0)
        ((float4*)sc)[wave * 64 + it * 8 + prow] = make_float4(s0, s1, s2, s3);
    }
  }
  __syncthreads();

  // ---- Phase 1.5: per-split softmax (wave w handles head w) ----
  {
    int h = wave;
    float vals[4];
    float m = -1e30f;
#pragma unroll
    for (int k = 0; k < 4; ++k) {
      vals[k] = sc[(k * 64 + lane) * 4 + h];
      m = fmaxf(m, vals[k]);
    }
#pragma unroll
    for (int mk = 1; mk <= 32; mk <<= 1) m = fmaxf(m, __shfl_xor(m, mk));
    float lsum = 0;
#pragma unroll
    for (int k = 0; k < 4; ++k) {
      float e = __expf(vals[k] - m);
      sc[(k * 64 + lane) * 4 + h] = e;
      lsum += e;
    }
#pragma unroll
    for (int mk = 1; mk <= 32; mk <<= 1) lsum += __shfl_xor(lsum, mk);
    if (lane == 0) {
      int hg = kvh * 4 + h;
      ml_ws[((size_t)(b * 32 + hg) * NSPLIT + split) * 2 + 0] = m;
      ml_ws[((size_t)(b * 32 + hg) * NSPLIT + split) * 2 + 1] = lsum;
    }
  }
  __syncthreads();

  // ---- Phase 2: PV. 2 rows/iter (half-wave each), float4 loads ----
  {
    const int dq = lane & 31;  // float4 column: d = dq*4
    const int half = lane >> 5;
    const float* vbase =
        cv + ((size_t)(b * 4096 + p0 + wave * 64 + half) * 8 + kvh) * 128 + dq * 4;
    float4 a0 = {0,0,0,0}, a1 = {0,0,0,0}, a2 = {0,0,0,0}, a3 = {0,0,0,0};
#pragma unroll 4
    for (int it = 0; it < 32; ++it) {
      int pl = wave * 64 + it * 2 + half;
      float4 v4 = *(const float4*)(vbase + it * 2 * 1024);
      float4 s4 = ((const float4*)sc)[pl];  // 2-way LDS broadcast (free)
      a0.x = fmaf(s4.x, v4.x, a0.x); a0.y = fmaf(s4.x, v4.y, a0.y);
      a0.z = fmaf(s4.x, v4.z, a0.z); a0.w = fmaf(s4.x, v4.w, a0.w);
      a1.x = fmaf(s4.y, v4.x, a1.x); a1.y = fmaf(s4.y, v4.y, a1.y);
      a1.z = fmaf(s4.y, v4.z, a1.z); a1.w = fmaf(s4.y, v4.w, a1.w);
      a2.x = fmaf(s4.z, v4.x, a2.x); a2.y = fmaf(s4.z, v4.y, a2.y);
      a2.z = fmaf(s4.z, v4.z, a2.z); a2.w = fmaf(s4.z, v4.w, a2.w);
      a3.x = fmaf(s4.w, v4.x, a3.x); a3.y = fmaf(s4.w, v4.y, a3.y);
      a3.z = fmaf(s4.w, v4.z, a3.z); a3.w = fmaf(s4.w, v4.w, a3.w);
    }
    int rb = (half * 16 + wave * 4) * 128 + dq * 4;
    *(float4*)&part[rb + 0 * 128] = a0;
    *(float4*)&part[rb + 1 * 128] = a1;
    *(float4*)&part[rb + 2 * 128] = a2;
    *(float4*)&part[rb + 3 * 128] = a3;
  }
  __syncthreads();
  {
    int hh = tid >> 6, dd = (tid & 63) * 2;
    float o0 = 0, o1 = 0;
#pragma unroll
    for (int g = 0; g < 8; ++g) {
      int row = (g >> 2) * 16 + (g & 3) * 4 + hh;
      float2 p2 = *(const float2*)&part[row * 128 + dd];
      o0 += p2.x; o1 += p2.y;
    }
    int hg = kvh * 4 + hh;
    size_t base = ((size_t)(b * 32 + hg) * NSPLIT + split) * 128;
    *(float2*)(opart + base + dd) = make_float2(o0, o1);
  }
}

// ---------------------------------------------------------------------------
// Kernel 3: combine split partials (flash rescale).
// ---------------------------------------------------------------------------
__global__ __launch_bounds__(128) void combine_kernel(
    const float* __restrict__ ml_ws, const float* __restrict__ opart,
    float* __restrict__ attn_ws) {
  int bh = blockIdx.x;  // b*32 + h
  int d = threadIdx.x;
  float mv[NSPLIT], lv[NSPLIT];
  float M = -1e30f;
#pragma unroll
  for (int i = 0; i < NSPLIT; ++i) {
    mv[i] = ml_ws[((size_t)bh * NSPLIT + i) * 2];
    lv[i] = ml_ws[((size_t)bh * NSPLIT + i) * 2 + 1];
    M = fmaxf(M, mv[i]);
  }
  float L = 0, o = 0;
#pragma unroll
  for (int i = 0; i < NSPLIT; ++i) {
    float w = __expf(mv[i] - M);
    L += w * lv[i];
    o += w * opart[((size_t)bh * NSPLIT + i) * 128 + d];
  }
  attn_ws[(size_t)bh * 128 + d] = o / L;
}

// ---------------------------------------------------------------------------
// Kernel 4: output projection with wo. 8 rows/block, 512 blocks.
// ---------------------------------------------------------------------------
__global__ __launch_bounds__(256) void oproj_kernel(
    const float* __restrict__ xin, const float* __restrict__ wo,
    float* __restrict__ out) {
  __shared__ float red[4][16 * RPAD];
  const int tid = threadIdx.x;
  const int lane = tid & 63;
  const int wave = tid >> 6;
  const int row0 = blockIdx.x * 8 + wave * 2;
  float res[2];
  gemv2_stream(xin, wo, row0, red[wave], res, lane);
  if ((lane & 3) == 0) {
    int b = lane >> 2;
    out[(size_t)b * 4096 + row0]     = res[0];
    out[(size_t)b * 4096 + row0 + 1] = res[1];
  }
}

extern "C" void kernel_launch(void* const* d_in, const int* in_sizes, int n_in,
                              void* d_out, int out_size, void* d_ws, size_t ws_size,
                              hipStream_t stream) {
  const float* x  = (const float*)d_in[0];
  const float* wq = (const float*)d_in[1];
  const float* wk = (const float*)d_in[2];
  const float* wv = (const float*)d_in[3];
  const float* wo = (const float*)d_in[4];
  float* ck = (float*)d_in[5];   // mutated in place at pos 4095 (idempotent;
  float* cv = (float*)d_in[6];   // harness restores inputs before each replay)
  const float* fc = (const float*)d_in[7];
  const float* fs = (const float*)d_in[8];

  float* ws      = (float*)d_ws;
  float* q_ws    = ws;               // 16*4096            = 65536
  float* ml_ws   = q_ws + 65536;     // 16*32*16*2         = 16384
  float* opart   = ml_ws + 16384;    // 16*32*16*128       = 1048576
  float* attn_ws = opart + 1048576;  // 16*4096            = 65536

  qkv_kernel<<<768, 256, 0, stream>>>(x, wq, wk, wv, fc, fs, q_ws, ck, cv);
  attn_kernel<<<dim3(NSPLIT, NKVH, BSZ), 256, 0, stream>>>(ck, cv, q_ws, ml_ws, opart);
  combine_kernel<<<BSZ * 32, 128, 0, stream>>>(ml_ws, opart, attn_ws);
  oproj_kernel<<<512, 256, 0, stream>>>(attn_ws, wo, (float*)d_out);
}